// Round 4
// baseline (129.432 us; speedup 1.0000x reference)
//
#include <hip/hip_runtime.h>

#define BB 32
#define NN 2048
#define DD 128
#define HH 8
#define KK 64

typedef __attribute__((ext_vector_type(8))) short bf16x8;
typedef __attribute__((ext_vector_type(4))) float f32x4;
#define MFMA_BF16 __builtin_amdgcn_mfma_f32_16x16x32_bf16

// ws layout (float units):
//   Gp_bf : [16][32][128][128] bf16 @ 0        (4194304 fl)
//   Mpt_bf: [32][8][128][128]  bf16 @ 4194304  (2097152 fl)   (stored [e][d])
//   Pbf   : [8][128][128]      bf16 @ 6291456  (65536 fl)

__device__ __forceinline__ float bf2f(unsigned short h){ return __uint_as_float(((unsigned)h) << 16); }
__device__ __forceinline__ unsigned short f2bf(float f){
  unsigned u = __float_as_uint(f);
  u += 0x7fffu + ((u >> 16) & 1u);   // RTNE
  return (unsigned short)(u >> 16);
}

// swizzled frag load: phys_ushort(r,c) = r*128 + ((c>>3)^(r&7))*8 + (c&7)
__device__ __forceinline__ bf16x8 ldfrag_sw(const unsigned short* base, int row16, int kc, int lane){
  int d = row16 + (lane & 15);
  int q = lane >> 4;
  int ch = ((kc << 2) + q) ^ (d & 7);
  return *(const bf16x8*)(base + d*128 + ch*8);
}
// padded frag load: row stride 136 ushorts
__device__ __forceinline__ bf16x8 ldfrag_pad(const unsigned short* base, int row16, int kc, int lane){
  int r = row16 + (lane & 15);
  int q = lane >> 4;
  return *(const bf16x8*)(base + r*136 + kc*32 + q*8);
}

// ---------------- K1: kg (blocks 0..511) + kp (512..543) ----------------
// kg: Gp_bf[chunk][b] = bf16( x_chunk^T @ x_chunk )  (hi/lo bf16 split, fp32 exact)
// kp: Pbf[h] = bf16( Wq[h]^T @ Wk[h] )
__global__ __launch_bounds__(256) void kgkp(const float* __restrict__ x,
                                            const float* __restrict__ Wq,
                                            const float* __restrict__ Wk,
                                            unsigned short* __restrict__ Gp_bf,
                                            unsigned short* __restrict__ Pbf){
  __shared__ __align__(16) unsigned short sm[32768];   // 64 KB
  const int t = threadIdx.x;
  const int bid = blockIdx.x;
  if (bid < 512){
    unsigned short* xh = sm;            // hi bf16, swizzled [d][n]
    unsigned short* xl = sm + 16384;    // lo
    const int b = bid & 31, chunk = bid >> 5;
    const float* xb = x + ((size_t)b*NN + (size_t)chunk*128)*DD;
    for (int it = 0; it < 4; ++it){
      int gidx = it*256 + t;
      int n4g = (gidx & 7) | (((gidx >> 6) & 3) << 3);
      int dcq = ((gidx >> 3) & 7) | (((gidx >> 8) & 3) << 3);
      float4 v[4];
      #pragma unroll
      for (int j = 0; j < 4; ++j)
        v[j] = *(const float4*)(xb + (size_t)(n4g*4 + j)*DD + dcq*4);
      #pragma unroll
      for (int i = 0; i < 4; ++i){
        int d = dcq*4 + i;
        float f0 = (&v[0].x)[i], f1 = (&v[1].x)[i], f2 = (&v[2].x)[i], f3 = (&v[3].x)[i];
        unsigned short h0 = f2bf(f0), h1 = f2bf(f1), h2 = f2bf(f2), h3 = f2bf(f3);
        unsigned short l0 = f2bf(f0 - bf2f(h0)), l1 = f2bf(f1 - bf2f(h1));
        unsigned short l2 = f2bf(f2 - bf2f(h2)), l3 = f2bf(f3 - bf2f(h3));
        int off = d*128 + ((((n4g >> 1) ^ (d & 7)) << 3) + (n4g & 1)*4);
        *(ushort4*)(xh + off) = make_ushort4(h0, h1, h2, h3);
        *(ushort4*)(xl + off) = make_ushort4(l0, l1, l2, l3);
      }
    }
    __syncthreads();
    const int w = t >> 6, lane = t & 63, quad = lane >> 4;
    const int wr = (w >> 1)*64, wc = (w & 1)*64;
    f32x4 acc[4][4] = {};
    for (int kc = 0; kc < 4; ++kc){
      bf16x8 ah[4], al[4], bh[4], bl[4];
      #pragma unroll
      for (int r = 0; r < 4; ++r){
        ah[r] = ldfrag_sw(xh, wr + r*16, kc, lane);
        al[r] = ldfrag_sw(xl, wr + r*16, kc, lane);
      }
      #pragma unroll
      for (int c = 0; c < 4; ++c){
        bh[c] = ldfrag_sw(xh, wc + c*16, kc, lane);
        bl[c] = ldfrag_sw(xl, wc + c*16, kc, lane);
      }
      #pragma unroll
      for (int r = 0; r < 4; ++r)
        #pragma unroll
        for (int c = 0; c < 4; ++c){
          acc[r][c] = MFMA_BF16(ah[r], bh[c], acc[r][c], 0, 0, 0);
          acc[r][c] = MFMA_BF16(ah[r], bl[c], acc[r][c], 0, 0, 0);
          acc[r][c] = MFMA_BF16(al[r], bh[c], acc[r][c], 0, 0, 0);
        }
    }
    // repack acc through LDS (fp32 [row][128]) -> coalesced bf16 stores
    __syncthreads();
    float* Sf = (float*)sm;    // 16384 floats = 64 KB
    #pragma unroll
    for (int r = 0; r < 4; ++r)
      #pragma unroll
      for (int c = 0; c < 4; ++c)
        #pragma unroll
        for (int reg = 0; reg < 4; ++reg)
          Sf[(wr + r*16 + quad*4 + reg)*128 + wc + c*16 + (lane & 15)] = acc[r][c][reg];
    __syncthreads();
    unsigned short* gp = Gp_bf + ((size_t)(chunk*32 + b) << 14);
    for (int i = t; i < 2048; i += 256){
      int r = i >> 4, c8 = (i & 15) * 8;
      const float* s = Sf + r*128 + c8;
      ushort4 lo = make_ushort4(f2bf(s[0]), f2bf(s[1]), f2bf(s[2]), f2bf(s[3]));
      ushort4 hi = make_ushort4(f2bf(s[4]), f2bf(s[5]), f2bf(s[6]), f2bf(s[7]));
      *(ushort4*)(gp + r*128 + c8)     = lo;
      *(ushort4*)(gp + r*128 + c8 + 4) = hi;
    }
  } else {
    // ---- kp ----
    float* Aq = (float*)sm;          // [64][36]
    float* Bk = Aq + 64*36;          // [64][132]
    const int kpid = bid - 512;
    const int h = kpid >> 2, rt = kpid & 3;
    const int i0 = rt * 32;
    const int tr = t >> 5, tc = t & 31;
    const float* wq = Wq + h*KK*DD;
    const float* wk = Wk + h*KK*DD;
    for (int i = t; i < 512; i += 256){
      int k = i >> 3, c4 = (i & 7) << 2;
      *(float4*)(&Aq[k*36 + c4]) = *(const float4*)(wq + k*DD + i0 + c4);
    }
    for (int i = t; i < 2048; i += 256){
      int k = i >> 5, c4 = (i & 31) << 2;
      *(float4*)(&Bk[k*132 + c4]) = *(const float4*)(wk + k*DD + c4);
    }
    __syncthreads();
    float acc[4][4] = {};
    for (int k = 0; k < 64; k += 2){
      float a0[4], b0[4], a1[4], b1[4];
      *(float4*)a0 = *(float4*)(&Aq[k*36 + tr*4]);
      *(float4*)b0 = *(float4*)(&Bk[k*132 + tc*4]);
      *(float4*)a1 = *(float4*)(&Aq[(k+1)*36 + tr*4]);
      *(float4*)b1 = *(float4*)(&Bk[(k+1)*132 + tc*4]);
      #pragma unroll
      for (int i = 0; i < 4; ++i)
        #pragma unroll
        for (int j = 0; j < 4; ++j){
          acc[i][j] += a0[i]*b0[j];
          acc[i][j] += a1[i]*b1[j];
        }
    }
    unsigned short* Ph = Pbf + h*DD*DD;
    #pragma unroll
    for (int i = 0; i < 4; ++i)
      *(ushort4*)(&Ph[(i0 + tr*4 + i)*DD + tc*4]) =
          make_ushort4(f2bf(acc[i][0]), f2bf(acc[i][1]), f2bf(acc[i][2]), f2bf(acc[i][3]));
  }
}

// ---------------- K2: per (b,h,eh): reduce Gp -> G; T = G@Wv^T; Mpt_bf[b][h] = bf16((P@T)^T) ----------------
__global__ __launch_bounds__(256) void km2(const unsigned short* __restrict__ Gp_bf,
                                           const float* __restrict__ Wv,
                                           const unsigned short* __restrict__ Pbf,
                                           unsigned short* __restrict__ Mpt_bf){
  __shared__ __align__(16) unsigned short As[128*136];  // G then P (bf16); epilogue float [64][132]
  __shared__ __align__(16) unsigned short Bs[64*136];   // Wv-half then T^T (bf16)
  const int bid = blockIdx.x;
  const int b = bid & 31, h = (bid >> 5) & 7, eh = bid >> 8;
  const int e0 = eh * 64;
  const int t = threadIdx.x;
  const int w = t >> 6, lane = t & 63, quad = lane >> 4;
  // reduce 16 bf16 G-partials (fp32 accum) straight into padded LDS
  for (int i = t; i < 2048; i += 256){
    int r = i >> 4, c8 = (i & 15) * 8;
    float s[8] = {};
    #pragma unroll
    for (int p = 0; p < 16; ++p){
      uint4 u = *(const uint4*)(Gp_bf + (((size_t)(p*32 + b)) << 14) + r*128 + c8);
      const unsigned short* pu = (const unsigned short*)&u;
      #pragma unroll
      for (int j = 0; j < 8; ++j) s[j] += bf2f(pu[j]);
    }
    ushort4 lo = make_ushort4(f2bf(s[0]), f2bf(s[1]), f2bf(s[2]), f2bf(s[3]));
    ushort4 hi = make_ushort4(f2bf(s[4]), f2bf(s[5]), f2bf(s[6]), f2bf(s[7]));
    *(ushort4*)(As + r*136 + c8)     = lo;
    *(ushort4*)(As + r*136 + c8 + 4) = hi;
  }
  const float* Wvh = Wv + ((size_t)h*DD + e0)*DD;
  for (int i = t; i < 2048; i += 256){
    int e = i >> 5, dc = (i & 31) * 4;
    float4 v = *(const float4*)(Wvh + (size_t)e*DD + dc);
    *(ushort4*)(Bs + e*136 + dc) = make_ushort4(f2bf(v.x), f2bf(v.y), f2bf(v.z), f2bf(v.w));
  }
  __syncthreads();
  // phase 1: T[c][e'] ([128]x[64]); wave = 64c x 32e quadrant
  const int wr = (w >> 1)*64, wc = (w & 1)*32;
  f32x4 acc1[4][2] = {};
  for (int kc = 0; kc < 4; ++kc){
    bf16x8 a[4], bb[2];
    #pragma unroll
    for (int r = 0; r < 4; ++r) a[r] = ldfrag_pad(As, wr + r*16, kc, lane);
    #pragma unroll
    for (int c = 0; c < 2; ++c) bb[c] = ldfrag_pad(Bs, wc + c*16, kc, lane);
    #pragma unroll
    for (int r = 0; r < 4; ++r)
      #pragma unroll
      for (int c = 0; c < 2; ++c)
        acc1[r][c] = MFMA_BF16(a[r], bb[c], acc1[r][c], 0, 0, 0);
  }
  __syncthreads();
  // T^T into Bs [e][c]; stage P into As
  #pragma unroll
  for (int r = 0; r < 4; ++r)
    #pragma unroll
    for (int c = 0; c < 2; ++c){
      int e = wc + c*16 + (lane & 15);
      int c0 = wr + r*16 + quad*4;
      *(ushort4*)(Bs + e*136 + c0) = make_ushort4(f2bf(acc1[r][c][0]), f2bf(acc1[r][c][1]),
                                                  f2bf(acc1[r][c][2]), f2bf(acc1[r][c][3]));
    }
  const unsigned short* Ph = Pbf + h*DD*DD;
  for (int i = t; i < 2048; i += 256){
    int r = i >> 4, ch = (i & 15) * 8;
    *(uint4*)(As + r*136 + ch) = *(const uint4*)(Ph + r*128 + ch);
  }
  __syncthreads();
  // phase 2: Mh[d][e'] = P @ T
  f32x4 acc2[4][2] = {};
  for (int kc = 0; kc < 4; ++kc){
    bf16x8 a[4], bb[2];
    #pragma unroll
    for (int r = 0; r < 4; ++r) a[r] = ldfrag_pad(As, wr + r*16, kc, lane);
    #pragma unroll
    for (int c = 0; c < 2; ++c) bb[c] = ldfrag_pad(Bs, wc + c*16, kc, lane);
    #pragma unroll
    for (int r = 0; r < 4; ++r)
      #pragma unroll
      for (int c = 0; c < 2; ++c)
        acc2[r][c] = MFMA_BF16(a[r], bb[c], acc2[r][c], 0, 0, 0);
  }
  __syncthreads();
  // transpose through LDS (float [e][132]), then coalesced bf16 store [e][d]
  float* Af = (float*)As;
  #pragma unroll
  for (int r = 0; r < 4; ++r)
    #pragma unroll
    for (int c = 0; c < 2; ++c){
      int e = wc + c*16 + (lane & 15);
      int d0 = wr + r*16 + quad*4;
      *(float4*)(Af + e*132 + d0) = make_float4(acc2[r][c][0], acc2[r][c][1], acc2[r][c][2], acc2[r][c][3]);
    }
  __syncthreads();
  unsigned short* Mb = Mpt_bf + (((size_t)(b*8 + h)) << 14);
  for (int i = t; i < 1024; i += 256){
    int e = i >> 4, c8 = (i & 15) * 8;
    const float* s = Af + e*132 + c8;
    ushort4 lo = make_ushort4(f2bf(s[0]), f2bf(s[1]), f2bf(s[2]), f2bf(s[3]));
    ushort4 hi = make_ushort4(f2bf(s[4]), f2bf(s[5]), f2bf(s[6]), f2bf(s[7]));
    *(ushort4*)(Mb + (e0 + e)*128 + c8)     = lo;
    *(ushort4*)(Mb + (e0 + e)*128 + c8 + 4) = hi;
  }
}

// ---------------- K3: reduce Mpt over h -> M^T; out[b,nt] = x_tile @ M ----------------
__global__ __launch_bounds__(256) void ko2(const float* __restrict__ x,
                                           const unsigned short* __restrict__ Mpt_bf,
                                           float* __restrict__ out){
  __shared__ __align__(16) unsigned short sm[32768];   // xs | Ms; epilogue float [n][128]
  unsigned short* xs = sm;           // x tile bf16, swizzled [n][d]
  unsigned short* Ms = sm + 16384;   // M^T bf16, swizzled [e][d]
  const int bid = blockIdx.x;
  const int b = bid & 31, nt = bid >> 5;
  const int t = threadIdx.x;
  const int w = t >> 6, lane = t & 63, quad = lane >> 4;
  const float* xb = x + ((size_t)b*NN + (size_t)nt*128)*DD;
  // stage x (cvt bf16, swizzled)
  for (int i = t; i < 4096; i += 256){
    int n = i >> 5, dcq = i & 31;
    float4 v = *(const float4*)(xb + (size_t)n*DD + dcq*4);
    int off = n*128 + ((((dcq >> 1) ^ (n & 7)) << 3) + (dcq & 1)*4);
    *(ushort4*)(xs + off) = make_ushort4(f2bf(v.x), f2bf(v.y), f2bf(v.z), f2bf(v.w));
  }
  // reduce 8 bf16 M^T-partials (fp32) into swizzled Ms
  for (int i = t; i < 2048; i += 256){
    int e = i >> 4, c8 = (i & 15) * 8;
    float s[8] = {};
    #pragma unroll
    for (int h = 0; h < 8; ++h){
      uint4 u = *(const uint4*)(Mpt_bf + (((size_t)(b*8 + h)) << 14) + e*128 + c8);
      const unsigned short* pu = (const unsigned short*)&u;
      #pragma unroll
      for (int j = 0; j < 8; ++j) s[j] += bf2f(pu[j]);
    }
    int off = e*128 + (((c8 >> 3) ^ (e & 7)) << 3);
    *(ushort4*)(Ms + off)     = make_ushort4(f2bf(s[0]), f2bf(s[1]), f2bf(s[2]), f2bf(s[3]));
    *(ushort4*)(Ms + off + 4) = make_ushort4(f2bf(s[4]), f2bf(s[5]), f2bf(s[6]), f2bf(s[7]));
  }
  __syncthreads();
  const int wr = (w >> 1)*64, wc = (w & 1)*64;
  f32x4 acc[4][4] = {};
  for (int kc = 0; kc < 4; ++kc){
    bf16x8 a[4], bb[4];
    #pragma unroll
    for (int r = 0; r < 4; ++r) a[r] = ldfrag_sw(xs, wr + r*16, kc, lane);
    #pragma unroll
    for (int c = 0; c < 4; ++c) bb[c] = ldfrag_sw(Ms, wc + c*16, kc, lane);
    #pragma unroll
    for (int r = 0; r < 4; ++r)
      #pragma unroll
      for (int c = 0; c < 4; ++c)
        acc[r][c] = MFMA_BF16(a[r], bb[c], acc[r][c], 0, 0, 0);
  }
  // repack out through LDS for coalesced float4 stores
  __syncthreads();
  float* Sf = (float*)sm;   // [n][128] fp32, 64 KB
  #pragma unroll
  for (int r = 0; r < 4; ++r)
    #pragma unroll
    for (int c = 0; c < 4; ++c)
      #pragma unroll
      for (int reg = 0; reg < 4; ++reg)
        Sf[(wr + r*16 + quad*4 + reg)*128 + wc + c*16 + (lane & 15)] = acc[r][c][reg];
  __syncthreads();
  float* ob = out + ((size_t)b*NN + (size_t)nt*128)*DD;
  for (int i = t; i < 4096; i += 256){
    int n = i >> 5, c4 = (i & 31) * 4;
    *(float4*)(ob + (size_t)n*DD + c4) = *(const float4*)(Sf + n*128 + c4);
  }
}

extern "C" void kernel_launch(void* const* d_in, const int* in_sizes, int n_in,
                              void* d_out, int out_size, void* d_ws, size_t ws_size,
                              hipStream_t stream){
  const float* x  = (const float*)d_in[0];
  const float* Wk = (const float*)d_in[1];
  const float* Wq = (const float*)d_in[2];
  const float* Wv = (const float*)d_in[3];
  float* out = (float*)d_out;
  float* ws = (float*)d_ws;
  unsigned short* Gp_bf  = (unsigned short*)ws;                 // 8388608 ushorts
  unsigned short* Mpt_bf = (unsigned short*)(ws + 4194304);     // 4194304 ushorts
  unsigned short* Pbf    = (unsigned short*)(ws + 6291456);     // 131072 ushorts

  kgkp<<<544, 256, 0, stream>>>(x, Wq, Wk, Gp_bf, Pbf);
  km2 <<<512, 256, 0, stream>>>(Gp_bf, Wv, Pbf, Mpt_bf);
  ko2 <<<512, 256, 0, stream>>>(x, Mpt_bf, out);
}

// Round 6
// 128.858 us; speedup vs baseline: 1.0045x; 1.0045x over previous
//
#include <hip/hip_runtime.h>

#define BB 32
#define NN 2048
#define DD 128
#define HH 8
#define KK 64

typedef __attribute__((ext_vector_type(8))) short bf16x8;
typedef __attribute__((ext_vector_type(4))) float f32x4;
#define MFMA_BF16 __builtin_amdgcn_mfma_f32_16x16x32_bf16

// ws layout (float units):
//   Gp_bf : [16][32][128][128] bf16 @ 0        (4194304 fl)
//   Mpt_bf: [32][8][128][128]  bf16 @ 4194304  (2097152 fl)   (stored [e][d])
//   Pbf   : [8][128][128]      bf16 @ 6291456  (65536 fl)

__device__ __forceinline__ float bf2f(unsigned short h){ return __uint_as_float(((unsigned)h) << 16); }
__device__ __forceinline__ unsigned short f2bf(float f){
  unsigned u = __float_as_uint(f);
  u += 0x7fffu + ((u >> 16) & 1u);   // RTNE
  return (unsigned short)(u >> 16);
}

// swizzled frag load: phys_ushort(r,c) = r*128 + ((c>>3)^(r&7))*8 + (c&7)
__device__ __forceinline__ bf16x8 ldfrag_sw(const unsigned short* base, int row16, int kc, int lane){
  int d = row16 + (lane & 15);
  int q = lane >> 4;
  int ch = ((kc << 2) + q) ^ (d & 7);
  return *(const bf16x8*)(base + d*128 + ch*8);
}
// padded frag load: row stride 136 ushorts
__device__ __forceinline__ bf16x8 ldfrag_pad(const unsigned short* base, int row16, int kc, int lane){
  int r = row16 + (lane & 15);
  int q = lane >> 4;
  return *(const bf16x8*)(base + r*136 + kc*32 + q*8);
}

// ---------------- K1: kg (blocks 0..511) + kp (512..543), 512 threads ----------------
__global__ __launch_bounds__(512, 4) void kgkp(const float* __restrict__ x,
                                               const float* __restrict__ Wq,
                                               const float* __restrict__ Wk,
                                               unsigned short* __restrict__ Gp_bf,
                                               unsigned short* __restrict__ Pbf){
  __shared__ __align__(16) unsigned short sm[32768];   // 64 KB
  const int t = threadIdx.x;
  const int bid = blockIdx.x;
  const int w = t >> 6, lane = t & 63, quad = lane >> 4;
  if (bid < 512){
    unsigned short* xh = sm;            // hi bf16, swizzled [d][n]
    unsigned short* xl = sm + 16384;    // lo
    const int b = bid & 31, chunk = bid >> 5;
    const float* xb = x + ((size_t)b*NN + (size_t)chunk*128)*DD;
    for (int it = 0; it < 2; ++it){
      int gidx = it*512 + t;
      int n4g = (gidx & 7) | (((gidx >> 6) & 3) << 3);
      int dcq = ((gidx >> 3) & 7) | (((gidx >> 8) & 3) << 3);
      float4 v[4];
      #pragma unroll
      for (int j = 0; j < 4; ++j)
        v[j] = *(const float4*)(xb + (size_t)(n4g*4 + j)*DD + dcq*4);
      #pragma unroll
      for (int i = 0; i < 4; ++i){
        int d = dcq*4 + i;
        float f0 = (&v[0].x)[i], f1 = (&v[1].x)[i], f2 = (&v[2].x)[i], f3 = (&v[3].x)[i];
        unsigned short h0 = f2bf(f0), h1 = f2bf(f1), h2 = f2bf(f2), h3 = f2bf(f3);
        unsigned short l0 = f2bf(f0 - bf2f(h0)), l1 = f2bf(f1 - bf2f(h1));
        unsigned short l2 = f2bf(f2 - bf2f(h2)), l3 = f2bf(f3 - bf2f(h3));
        int off = d*128 + ((((n4g >> 1) ^ (d & 7)) << 3) + (n4g & 1)*4);
        *(ushort4*)(xh + off) = make_ushort4(h0, h1, h2, h3);
        *(ushort4*)(xl + off) = make_ushort4(l0, l1, l2, l3);
      }
    }
    __syncthreads();
    // 8 waves: rows (w>>1)*32 (2 tiles), cols (w&1)*64 (4 tiles)
    const int wr = (w >> 1)*32, wc = (w & 1)*64;
    f32x4 acc[2][4] = {};
    for (int kc = 0; kc < 4; ++kc){
      bf16x8 ah[2], al[2], bh[4], bl[4];
      #pragma unroll
      for (int r = 0; r < 2; ++r){
        ah[r] = ldfrag_sw(xh, wr + r*16, kc, lane);
        al[r] = ldfrag_sw(xl, wr + r*16, kc, lane);
      }
      #pragma unroll
      for (int c = 0; c < 4; ++c){
        bh[c] = ldfrag_sw(xh, wc + c*16, kc, lane);
        bl[c] = ldfrag_sw(xl, wc + c*16, kc, lane);
      }
      #pragma unroll
      for (int r = 0; r < 2; ++r)
        #pragma unroll
        for (int c = 0; c < 4; ++c){
          acc[r][c] = MFMA_BF16(ah[r], bh[c], acc[r][c], 0, 0, 0);
          acc[r][c] = MFMA_BF16(ah[r], bl[c], acc[r][c], 0, 0, 0);
          acc[r][c] = MFMA_BF16(al[r], bh[c], acc[r][c], 0, 0, 0);
        }
    }
    __syncthreads();
    float* Sf = (float*)sm;    // fp32 [128][128] = 64 KB
    #pragma unroll
    for (int r = 0; r < 2; ++r)
      #pragma unroll
      for (int c = 0; c < 4; ++c)
        #pragma unroll
        for (int reg = 0; reg < 4; ++reg)
          Sf[(wr + r*16 + quad*4 + reg)*128 + wc + c*16 + (lane & 15)] = acc[r][c][reg];
    __syncthreads();
    unsigned short* gp = Gp_bf + ((size_t)(chunk*32 + b) << 14);
    for (int i = t; i < 2048; i += 512){
      int r = i >> 4, c8 = (i & 15) * 8;
      const float* s = Sf + r*128 + c8;
      *(ushort4*)(gp + r*128 + c8)     = make_ushort4(f2bf(s[0]), f2bf(s[1]), f2bf(s[2]), f2bf(s[3]));
      *(ushort4*)(gp + r*128 + c8 + 4) = make_ushort4(f2bf(s[4]), f2bf(s[5]), f2bf(s[6]), f2bf(s[7]));
    }
  } else {
    // ---- kp, 512 threads: tr = t>>6 (8 row-groups of 4), tc = t&63 (2-col tiles) ----
    float* Aq = (float*)sm;          // [64][36]
    float* Bk = Aq + 64*36;          // [64][132]
    const int kpid = bid - 512;
    const int h = kpid >> 2, rt = kpid & 3;
    const int i0 = rt * 32;
    const int tr = t >> 6, tc = t & 63;
    const float* wq = Wq + h*KK*DD;
    const float* wk = Wk + h*KK*DD;
    for (int i = t; i < 512; i += 512){
      int k = i >> 3, c4 = (i & 7) << 2;
      *(float4*)(&Aq[k*36 + c4]) = *(const float4*)(wq + k*DD + i0 + c4);
    }
    for (int i = t; i < 2048; i += 512){
      int k = i >> 5, c4 = (i & 31) << 2;
      *(float4*)(&Bk[k*132 + c4]) = *(const float4*)(wk + k*DD + c4);
    }
    __syncthreads();
    float acc[4][2] = {};
    for (int k = 0; k < 64; k += 2){
      float a0[4], a1[4], b0[2], b1[2];
      *(float4*)a0 = *(float4*)(&Aq[k*36 + tr*4]);
      *(float4*)a1 = *(float4*)(&Aq[(k+1)*36 + tr*4]);
      b0[0] = Bk[k*132 + tc*2];     b0[1] = Bk[k*132 + tc*2 + 1];
      b1[0] = Bk[(k+1)*132 + tc*2]; b1[1] = Bk[(k+1)*132 + tc*2 + 1];
      #pragma unroll
      for (int i = 0; i < 4; ++i)
        #pragma unroll
        for (int j = 0; j < 2; ++j){
          acc[i][j] += a0[i]*b0[j];
          acc[i][j] += a1[i]*b1[j];
        }
    }
    unsigned short* Ph = Pbf + h*DD*DD;
    #pragma unroll
    for (int i = 0; i < 4; ++i)
      *(ushort2*)(&Ph[(i0 + tr*4 + i)*DD + tc*2]) =
          make_ushort2(f2bf(acc[i][0]), f2bf(acc[i][1]));
  }
}

// ---------------- K2: per (b,h,eh): reduce Gp; T = G@Wv^T; Mpt_bf = bf16((P@T)^T). 512 thr ----------------
__global__ __launch_bounds__(512, 4) void km2(const unsigned short* __restrict__ Gp_bf,
                                              const float* __restrict__ Wv,
                                              const unsigned short* __restrict__ Pbf,
                                              unsigned short* __restrict__ Mpt_bf){
  __shared__ __align__(16) unsigned short As[128*136];  // G then P (bf16); epilogue float [64][132]
  __shared__ __align__(16) unsigned short Bs[64*136];   // Wv-half then T^T (bf16)
  const int bid = blockIdx.x;
  const int b = bid & 31, h = (bid >> 5) & 7, eh = bid >> 8;
  const int e0 = eh * 64;
  const int t = threadIdx.x;
  const int w = t >> 6, lane = t & 63, quad = lane >> 4;
  for (int i = t; i < 2048; i += 512){
    int r = i >> 4, c8 = (i & 15) * 8;
    float s[8] = {};
    #pragma unroll
    for (int p = 0; p < 16; ++p){
      uint4 u = *(const uint4*)(Gp_bf + (((size_t)(p*32 + b)) << 14) + r*128 + c8);
      const unsigned short* pu = (const unsigned short*)&u;
      #pragma unroll
      for (int j = 0; j < 8; ++j) s[j] += bf2f(pu[j]);
    }
    *(ushort4*)(As + r*136 + c8)     = make_ushort4(f2bf(s[0]), f2bf(s[1]), f2bf(s[2]), f2bf(s[3]));
    *(ushort4*)(As + r*136 + c8 + 4) = make_ushort4(f2bf(s[4]), f2bf(s[5]), f2bf(s[6]), f2bf(s[7]));
  }
  const float* Wvh = Wv + ((size_t)h*DD + e0)*DD;
  for (int i = t; i < 2048; i += 512){
    int e = i >> 5, dc = (i & 31) * 4;
    float4 v = *(const float4*)(Wvh + (size_t)e*DD + dc);
    *(ushort4*)(Bs + e*136 + dc) = make_ushort4(f2bf(v.x), f2bf(v.y), f2bf(v.z), f2bf(v.w));
  }
  __syncthreads();
  // 8 waves: rows (w>>1)*32 (2 tiles), cols (w&1)*32 (2 tiles)
  const int wr = (w >> 1)*32, wc = (w & 1)*32;
  f32x4 acc1[2][2] = {};
  for (int kc = 0; kc < 4; ++kc){
    bf16x8 a[2], bb[2];
    #pragma unroll
    for (int r = 0; r < 2; ++r) a[r] = ldfrag_pad(As, wr + r*16, kc, lane);
    #pragma unroll
    for (int c = 0; c < 2; ++c) bb[c] = ldfrag_pad(Bs, wc + c*16, kc, lane);
    #pragma unroll
    for (int r = 0; r < 2; ++r)
      #pragma unroll
      for (int c = 0; c < 2; ++c)
        acc1[r][c] = MFMA_BF16(a[r], bb[c], acc1[r][c], 0, 0, 0);
  }
  __syncthreads();
  // T^T into Bs [e][c]; stage P into As
  #pragma unroll
  for (int r = 0; r < 2; ++r)
    #pragma unroll
    for (int c = 0; c < 2; ++c){
      int e = wc + c*16 + (lane & 15);
      int c0 = wr + r*16 + quad*4;
      *(ushort4*)(Bs + e*136 + c0) = make_ushort4(f2bf(acc1[r][c][0]), f2bf(acc1[r][c][1]),
                                                  f2bf(acc1[r][c][2]), f2bf(acc1[r][c][3]));
    }
  const unsigned short* Ph = Pbf + h*DD*DD;
  for (int i = t; i < 2048; i += 512){
    int r = i >> 4, ch = (i & 15) * 8;
    *(uint4*)(As + r*136 + ch) = *(const uint4*)(Ph + r*128 + ch);
  }
  __syncthreads();
  f32x4 acc2[2][2] = {};
  for (int kc = 0; kc < 4; ++kc){
    bf16x8 a[2], bb[2];
    #pragma unroll
    for (int r = 0; r < 2; ++r) a[r] = ldfrag_pad(As, wr + r*16, kc, lane);
    #pragma unroll
    for (int c = 0; c < 2; ++c) bb[c] = ldfrag_pad(Bs, wc + c*16, kc, lane);
    #pragma unroll
    for (int r = 0; r < 2; ++r)
      #pragma unroll
      for (int c = 0; c < 2; ++c)
        acc2[r][c] = MFMA_BF16(a[r], bb[c], acc2[r][c], 0, 0, 0);
  }
  __syncthreads();
  // transpose through LDS (float [e][132]) -> coalesced bf16 store [e][d]
  float* Af = (float*)As;
  #pragma unroll
  for (int r = 0; r < 2; ++r)
    #pragma unroll
    for (int c = 0; c < 2; ++c){
      int e = wc + c*16 + (lane & 15);
      int d0 = wr + r*16 + quad*4;
      *(float4*)(Af + e*132 + d0) = make_float4(acc2[r][c][0], acc2[r][c][1], acc2[r][c][2], acc2[r][c][3]);
    }
  __syncthreads();
  unsigned short* Mb = Mpt_bf + (((size_t)(b*8 + h)) << 14);
  for (int i = t; i < 1024; i += 512){
    int e = i >> 4, c8 = (i & 15) * 8;
    const float* s = Af + e*132 + c8;
    *(ushort4*)(Mb + (e0 + e)*128 + c8)     = make_ushort4(f2bf(s[0]), f2bf(s[1]), f2bf(s[2]), f2bf(s[3]));
    *(ushort4*)(Mb + (e0 + e)*128 + c8 + 4) = make_ushort4(f2bf(s[4]), f2bf(s[5]), f2bf(s[6]), f2bf(s[7]));
  }
}

// ---------------- K3: reduce Mpt over h -> M^T; out = x_tile @ M. 512 threads ----------------
__global__ __launch_bounds__(512, 4) void ko2(const float* __restrict__ x,
                                              const unsigned short* __restrict__ Mpt_bf,
                                              float* __restrict__ out){
  __shared__ __align__(16) unsigned short sm[32768];   // xs | Ms; epilogue float [n][128]
  unsigned short* xs = sm;           // x tile bf16, swizzled [n][d]
  unsigned short* Ms = sm + 16384;   // M^T bf16, swizzled [e][d]
  const int bid = blockIdx.x;
  const int b = bid & 31, nt = bid >> 5;
  const int t = threadIdx.x;
  const int w = t >> 6, lane = t & 63, quad = lane >> 4;
  const float* xb = x + ((size_t)b*NN + (size_t)nt*128)*DD;
  for (int i = t; i < 4096; i += 512){
    int n = i >> 5, dcq = i & 31;
    float4 v = *(const float4*)(xb + (size_t)n*DD + dcq*4);
    int off = n*128 + ((((dcq >> 1) ^ (n & 7)) << 3) + (dcq & 1)*4);
    *(ushort4*)(xs + off) = make_ushort4(f2bf(v.x), f2bf(v.y), f2bf(v.z), f2bf(v.w));
  }
  for (int i = t; i < 2048; i += 512){
    int e = i >> 4, c8 = (i & 15) * 8;
    float s[8] = {};
    #pragma unroll
    for (int h = 0; h < 8; ++h){
      uint4 u = *(const uint4*)(Mpt_bf + (((size_t)(b*8 + h)) << 14) + e*128 + c8);
      const unsigned short* pu = (const unsigned short*)&u;
      #pragma unroll
      for (int j = 0; j < 8; ++j) s[j] += bf2f(pu[j]);
    }
    int off = e*128 + (((c8 >> 3) ^ (e & 7)) << 3);
    *(ushort4*)(Ms + off)     = make_ushort4(f2bf(s[0]), f2bf(s[1]), f2bf(s[2]), f2bf(s[3]));
    *(ushort4*)(Ms + off + 4) = make_ushort4(f2bf(s[4]), f2bf(s[5]), f2bf(s[6]), f2bf(s[7]));
  }
  __syncthreads();
  // 8 waves: rows (w>>1)*32 (2 tiles), cols (w&1)*64 (4 tiles)
  const int wr = (w >> 1)*32, wc = (w & 1)*64;
  f32x4 acc[2][4] = {};
  for (int kc = 0; kc < 4; ++kc){
    bf16x8 a[2], bb[4];
    #pragma unroll
    for (int r = 0; r < 2; ++r) a[r] = ldfrag_sw(xs, wr + r*16, kc, lane);
    #pragma unroll
    for (int c = 0; c < 4; ++c) bb[c] = ldfrag_sw(Ms, wc + c*16, kc, lane);
    #pragma unroll
    for (int r = 0; r < 2; ++r)
      #pragma unroll
      for (int c = 0; c < 4; ++c)
        acc[r][c] = MFMA_BF16(a[r], bb[c], acc[r][c], 0, 0, 0);
  }
  __syncthreads();
  float* Sf = (float*)sm;   // [n][128] fp32, 64 KB
  #pragma unroll
  for (int r = 0; r < 2; ++r)
    #pragma unroll
    for (int c = 0; c < 4; ++c)
      #pragma unroll
      for (int reg = 0; reg < 4; ++reg)
        Sf[(wr + r*16 + quad*4 + reg)*128 + wc + c*16 + (lane & 15)] = acc[r][c][reg];
  __syncthreads();
  float* ob = out + ((size_t)b*NN + (size_t)nt*128)*DD;
  for (int i = t; i < 4096; i += 512){
    int n = i >> 5, c4 = (i & 31) * 4;
    *(float4*)(ob + (size_t)n*DD + c4) = *(const float4*)(Sf + n*128 + c4);
  }
}

extern "C" void kernel_launch(void* const* d_in, const int* in_sizes, int n_in,
                              void* d_out, int out_size, void* d_ws, size_t ws_size,
                              hipStream_t stream){
  const float* x  = (const float*)d_in[0];
  const float* Wk = (const float*)d_in[1];
  const float* Wq = (const float*)d_in[2];
  const float* Wv = (const float*)d_in[3];
  float* out = (float*)d_out;
  float* ws = (float*)d_ws;
  unsigned short* Gp_bf  = (unsigned short*)ws;                 // 8388608 ushorts
  unsigned short* Mpt_bf = (unsigned short*)(ws + 4194304);     // 4194304 ushorts
  unsigned short* Pbf    = (unsigned short*)(ws + 6291456);     // 131072 ushorts

  kgkp<<<544, 512, 0, stream>>>(x, Wq, Wk, Gp_bf, Pbf);
  km2 <<<512, 512, 0, stream>>>(Gp_bf, Wv, Pbf, Mpt_bf);
  ko2 <<<512, 512, 0, stream>>>(x, Mpt_bf, out);
}

// Round 7
// 123.482 us; speedup vs baseline: 1.0482x; 1.0435x over previous
//
#include <hip/hip_runtime.h>

#define BB 32
#define NN 2048
#define DD 128
#define HH 8
#define KK 64

typedef __attribute__((ext_vector_type(8))) short bf16x8;
typedef __attribute__((ext_vector_type(4))) float f32x4;
#define MFMA_BF16 __builtin_amdgcn_mfma_f32_16x16x32_bf16

// ws layout (ushort units):
//   Gp_bf : [8][32][128][128]  @ 0        (4194304)
//   Mp_bf : [32][8][128][128]  @ 4194304  (4194304)   (natural [d][e])
//   Pbf   : [8][128][128]      @ 8388608  (131072)
//   Mtbf  : [32][128][128]     @ 8519680  (524288)    (transposed [e][d])

__device__ __forceinline__ float bf2f(unsigned short h){ return __uint_as_float(((unsigned)h) << 16); }
__device__ __forceinline__ unsigned short f2bf(float f){
  unsigned u = __float_as_uint(f);
  u += 0x7fffu + ((u >> 16) & 1u);   // RTNE
  return (unsigned short)(u >> 16);
}
__device__ __forceinline__ unsigned pack2(float a, float b){
  return (unsigned)f2bf(a) | ((unsigned)f2bf(b) << 16);
}

// swizzled frag load: phys_ushort(r,c) = r*128 + ((c>>3)^(r&7))*8 + (c&7)
__device__ __forceinline__ bf16x8 ldfrag_sw(const unsigned short* base, int row16, int kc, int lane){
  int d = row16 + (lane & 15);
  int q = lane >> 4;
  int ch = ((kc << 2) + q) ^ (d & 7);
  return *(const bf16x8*)(base + d*128 + ch*8);
}

// ---------------- K1: kg (blocks 0..255, 256-row chunks) + kp (256..287) ----------------
__global__ __launch_bounds__(512, 4) void kgkp(const float* __restrict__ x,
                                               const float* __restrict__ Wq,
                                               const float* __restrict__ Wk,
                                               unsigned short* __restrict__ Gp_bf,
                                               unsigned short* __restrict__ Pbf){
  __shared__ __align__(16) unsigned short sm[32768];   // 64 KB
  const int t = threadIdx.x;
  const int bid = blockIdx.x;
  const int w = t >> 6, lane = t & 63, quad = lane >> 4;
  if (bid < 256){
    unsigned short* xh = sm;            // hi bf16, swizzled [d][n]
    unsigned short* xl = sm + 16384;    // lo
    const int b = bid & 31, chunk = bid >> 5;          // chunk in [0,8), 256 rows
    const int wr = (w >> 1)*32, wc = (w & 1)*64;
    f32x4 acc[2][4] = {};
    for (int sub = 0; sub < 2; ++sub){
      if (sub) __syncthreads();
      const float* xb = x + ((size_t)b*NN + (size_t)(chunk*256 + sub*128))*DD;
      for (int it = 0; it < 2; ++it){
        int gidx = it*512 + t;
        int n4g = (gidx & 7) | (((gidx >> 6) & 3) << 3);
        int dcq = ((gidx >> 3) & 7) | (((gidx >> 8) & 3) << 3);
        float4 v[4];
        #pragma unroll
        for (int j = 0; j < 4; ++j)
          v[j] = *(const float4*)(xb + (size_t)(n4g*4 + j)*DD + dcq*4);
        #pragma unroll
        for (int i = 0; i < 4; ++i){
          int d = dcq*4 + i;
          float f0 = (&v[0].x)[i], f1 = (&v[1].x)[i], f2 = (&v[2].x)[i], f3 = (&v[3].x)[i];
          unsigned short h0 = f2bf(f0), h1 = f2bf(f1), h2 = f2bf(f2), h3 = f2bf(f3);
          unsigned short l0 = f2bf(f0 - bf2f(h0)), l1 = f2bf(f1 - bf2f(h1));
          unsigned short l2 = f2bf(f2 - bf2f(h2)), l3 = f2bf(f3 - bf2f(h3));
          int off = d*128 + ((((n4g >> 1) ^ (d & 7)) << 3) + (n4g & 1)*4);
          *(ushort4*)(xh + off) = make_ushort4(h0, h1, h2, h3);
          *(ushort4*)(xl + off) = make_ushort4(l0, l1, l2, l3);
        }
      }
      __syncthreads();
      for (int kc = 0; kc < 4; ++kc){
        bf16x8 ah[2], al[2], bh[4], bl[4];
        #pragma unroll
        for (int r = 0; r < 2; ++r){
          ah[r] = ldfrag_sw(xh, wr + r*16, kc, lane);
          al[r] = ldfrag_sw(xl, wr + r*16, kc, lane);
        }
        #pragma unroll
        for (int c = 0; c < 4; ++c){
          bh[c] = ldfrag_sw(xh, wc + c*16, kc, lane);
          bl[c] = ldfrag_sw(xl, wc + c*16, kc, lane);
        }
        #pragma unroll
        for (int r = 0; r < 2; ++r)
          #pragma unroll
          for (int c = 0; c < 4; ++c){
            acc[r][c] = MFMA_BF16(ah[r], bh[c], acc[r][c], 0, 0, 0);
            acc[r][c] = MFMA_BF16(ah[r], bl[c], acc[r][c], 0, 0, 0);
            acc[r][c] = MFMA_BF16(al[r], bh[c], acc[r][c], 0, 0, 0);
          }
      }
    }
    __syncthreads();
    float* Sf = (float*)sm;    // fp32 [128][128] = 64 KB
    #pragma unroll
    for (int r = 0; r < 2; ++r)
      #pragma unroll
      for (int c = 0; c < 4; ++c)
        #pragma unroll
        for (int reg = 0; reg < 4; ++reg)
          Sf[(wr + r*16 + quad*4 + reg)*128 + wc + c*16 + (lane & 15)] = acc[r][c][reg];
    __syncthreads();
    unsigned short* gp = Gp_bf + ((size_t)(chunk*32 + b) << 14);
    for (int i = t; i < 2048; i += 512){
      int r = i >> 4, c8 = (i & 15) * 8;
      const float* s = Sf + r*128 + c8;
      uint4 o;
      o.x = pack2(s[0], s[1]); o.y = pack2(s[2], s[3]);
      o.z = pack2(s[4], s[5]); o.w = pack2(s[6], s[7]);
      *(uint4*)(gp + r*128 + c8) = o;
    }
  } else {
    // ---- kp: P[h] = Wq^T Wk, 32 blocks, 512 threads ----
    float* Aq = (float*)sm;          // [64][36]
    float* Bk = Aq + 64*36;          // [64][132]
    const int kpid = bid - 256;
    const int h = kpid >> 2, rt = kpid & 3;
    const int i0 = rt * 32;
    const int tr = t >> 6, tc = t & 63;
    const float* wq = Wq + h*KK*DD;
    const float* wk = Wk + h*KK*DD;
    for (int i = t; i < 512; i += 512){
      int k = i >> 3, c4 = (i & 7) << 2;
      *(float4*)(&Aq[k*36 + c4]) = *(const float4*)(wq + k*DD + i0 + c4);
    }
    for (int i = t; i < 2048; i += 512){
      int k = i >> 5, c4 = (i & 31) << 2;
      *(float4*)(&Bk[k*132 + c4]) = *(const float4*)(wk + k*DD + c4);
    }
    __syncthreads();
    float acc[4][2] = {};
    for (int k = 0; k < 64; k += 2){
      float a0[4], a1[4], b0[2], b1[2];
      *(float4*)a0 = *(float4*)(&Aq[k*36 + tr*4]);
      *(float4*)a1 = *(float4*)(&Aq[(k+1)*36 + tr*4]);
      b0[0] = Bk[k*132 + tc*2];     b0[1] = Bk[k*132 + tc*2 + 1];
      b1[0] = Bk[(k+1)*132 + tc*2]; b1[1] = Bk[(k+1)*132 + tc*2 + 1];
      #pragma unroll
      for (int i = 0; i < 4; ++i)
        #pragma unroll
        for (int j = 0; j < 2; ++j){
          acc[i][j] += a0[i]*b0[j];
          acc[i][j] += a1[i]*b1[j];
        }
    }
    unsigned short* Ph = Pbf + h*DD*DD;
    #pragma unroll
    for (int i = 0; i < 4; ++i)
      *(ushort2*)(&Ph[(i0 + tr*4 + i)*DD + tc*2]) =
          make_ushort2(f2bf(acc[i][0]), f2bf(acc[i][1]));
  }
}

// ---------------- K2: per (b,h): reduce Gp->G; T = G@Wv^T (full); M = P@T (full) ----------------
__global__ __launch_bounds__(512, 2) void km2(const unsigned short* __restrict__ Gp_bf,
                                              const float* __restrict__ Wv,
                                              const unsigned short* __restrict__ Pbf,
                                              unsigned short* __restrict__ Mp_bf){
  __shared__ __align__(16) unsigned short sm[32768];   // As | Bs, 64 KB
  unsigned short* As = sm;           // G then P, swizzled [d][k]
  unsigned short* Bs = sm + 16384;   // Wv then T^T, swizzled [e][k]
  const int bid = blockIdx.x;
  const int b = bid & 31, h = bid >> 5;
  const int t = threadIdx.x;
  const int w = t >> 6, lane = t & 63, quad = lane >> 4;
  // reduce 8 bf16 G-partials (fp32) -> As swizzled
  for (int i = t; i < 2048; i += 512){
    int r = i >> 4, c8 = (i & 15) * 8;
    float s[8] = {};
    #pragma unroll
    for (int p = 0; p < 8; ++p){
      uint4 u = *(const uint4*)(Gp_bf + (((size_t)(p*32 + b)) << 14) + r*128 + c8);
      const unsigned short* pu = (const unsigned short*)&u;
      #pragma unroll
      for (int j = 0; j < 8; ++j) s[j] += bf2f(pu[j]);
    }
    uint4 o;
    o.x = pack2(s[0], s[1]); o.y = pack2(s[2], s[3]);
    o.z = pack2(s[4], s[5]); o.w = pack2(s[6], s[7]);
    *(uint4*)(As + r*128 + ((((c8 >> 3) ^ (r & 7))) << 3)) = o;
  }
  // stage Wv[h] full (cvt bf16, swizzled [e][d'])
  const float* Wvh = Wv + (size_t)h*DD*DD;
  for (int i = t; i < 4096; i += 512){
    int e = i >> 5, dc = (i & 31) * 4;
    float4 v = *(const float4*)(Wvh + (size_t)e*DD + dc);
    int off = e*128 + ((((dc >> 3) ^ (e & 7)) << 3) + (dc & 4));
    *(ushort4*)(Bs + off) = make_ushort4(f2bf(v.x), f2bf(v.y), f2bf(v.z), f2bf(v.w));
  }
  __syncthreads();
  // phase 1: T[d][e] = G @ Wv^T; wave w owns d-tile w, all 8 e-tiles
  f32x4 acc1[8] = {};
  for (int kc = 0; kc < 4; ++kc){
    bf16x8 a = ldfrag_sw(As, w*16, kc, lane);
    bf16x8 bb[8];
    #pragma unroll
    for (int c = 0; c < 8; ++c) bb[c] = ldfrag_sw(Bs, c*16, kc, lane);
    #pragma unroll
    for (int c = 0; c < 8; ++c) acc1[c] = MFMA_BF16(a, bb[c], acc1[c], 0, 0, 0);
  }
  __syncthreads();
  // write T^T into Bs (swizzled [e][c]); stage P into As
  #pragma unroll
  for (int c = 0; c < 8; ++c){
    int e = c*16 + (lane & 15);
    int d0 = w*16 + quad*4;
    int off = e*128 + ((((d0 >> 3) ^ (e & 7)) << 3) + (d0 & 7));
    *(ushort4*)(Bs + off) = make_ushort4(f2bf(acc1[c][0]), f2bf(acc1[c][1]),
                                         f2bf(acc1[c][2]), f2bf(acc1[c][3]));
  }
  const unsigned short* Ph = Pbf + (size_t)h*DD*DD;
  for (int i = t; i < 2048; i += 512){
    int r = i >> 4, ch = i & 15;
    *(uint4*)(As + r*128 + ((ch ^ (r & 7)) << 3)) = *(const uint4*)(Ph + r*128 + ch*8);
  }
  __syncthreads();
  // phase 2: M[d][e] = P @ T
  f32x4 acc2[8] = {};
  for (int kc = 0; kc < 4; ++kc){
    bf16x8 a = ldfrag_sw(As, w*16, kc, lane);
    bf16x8 bb[8];
    #pragma unroll
    for (int c = 0; c < 8; ++c) bb[c] = ldfrag_sw(Bs, c*16, kc, lane);
    #pragma unroll
    for (int c = 0; c < 8; ++c) acc2[c] = MFMA_BF16(a, bb[c], acc2[c], 0, 0, 0);
  }
  __syncthreads();
  // epilogue: repack through fp32 LDS -> coalesced bf16 store (natural [d][e])
  float* Sf = (float*)sm;   // [128][128] fp32 = 64 KB
  #pragma unroll
  for (int c = 0; c < 8; ++c)
    #pragma unroll
    for (int reg = 0; reg < 4; ++reg)
      Sf[(w*16 + quad*4 + reg)*128 + c*16 + (lane & 15)] = acc2[c][reg];
  __syncthreads();
  unsigned short* Mb = Mp_bf + (((size_t)(b*8 + h)) << 14);
  for (int i = t; i < 2048; i += 512){
    int r = i >> 4, c8 = (i & 15) * 8;
    const float* s = Sf + r*128 + c8;
    uint4 o;
    o.x = pack2(s[0], s[1]); o.y = pack2(s[2], s[3]);
    o.z = pack2(s[4], s[5]); o.w = pack2(s[6], s[7]);
    *(uint4*)(Mb + r*128 + c8) = o;
  }
}

// ---------------- K3: kmr — reduce Mp over h + transpose -> Mtbf[b][e][d] ----------------
__global__ __launch_bounds__(256) void kmr(const unsigned short* __restrict__ Mp_bf,
                                           unsigned short* __restrict__ Mtbf){
  __shared__ float Sf[16][132];
  const int bid = blockIdx.x;
  const int b = bid >> 3, es = bid & 7;       // e-strip of 16
  const int t = threadIdx.x;
  {
    int d = t >> 1, half = t & 1;             // 256 threads cover 128 d x 2 halves
    float s[8] = {};
    #pragma unroll
    for (int h = 0; h < 8; ++h){
      uint4 u = *(const uint4*)(Mp_bf + (((size_t)(b*8 + h)) << 14) + d*128 + es*16 + half*8);
      const unsigned short* pu = (const unsigned short*)&u;
      #pragma unroll
      for (int j = 0; j < 8; ++j) s[j] += bf2f(pu[j]);
    }
    #pragma unroll
    for (int j = 0; j < 8; ++j) Sf[half*8 + j][d] = s[j];
  }
  __syncthreads();
  unsigned short* Mb = Mtbf + ((size_t)b << 14);
  for (int j = t; j < 2048; j += 256){
    int e = j >> 7, d = j & 127;
    Mb[(es*16 + e)*128 + d] = f2bf(Sf[e][d]);
  }
}

// ---------------- K4: ko — out[b,nt] = x_tile @ M (B staged from Mtbf, pure copies) ----------------
__global__ __launch_bounds__(512, 4) void ko2(const float* __restrict__ x,
                                              const unsigned short* __restrict__ Mtbf,
                                              float* __restrict__ out){
  __shared__ __align__(16) unsigned short sm[32768];   // xs | Ms; epilogue float [n][128]
  unsigned short* xs = sm;           // x tile bf16, swizzled [n][d]
  unsigned short* Ms = sm + 16384;   // M^T bf16, swizzled [e][d]
  const int bid = blockIdx.x;
  const int b = bid & 31, nt = bid >> 5;
  const int t = threadIdx.x;
  const int w = t >> 6, lane = t & 63, quad = lane >> 4;
  const float* xb = x + ((size_t)b*NN + (size_t)nt*128)*DD;
  const unsigned short* Mtb = Mtbf + ((size_t)b << 14);
  for (int i = t; i < 4096; i += 512){
    int n = i >> 5, dcq = i & 31;
    float4 v = *(const float4*)(xb + (size_t)n*DD + dcq*4);
    int off = n*128 + ((((dcq >> 1) ^ (n & 7)) << 3) + (dcq & 1)*4);
    *(ushort4*)(xs + off) = make_ushort4(f2bf(v.x), f2bf(v.y), f2bf(v.z), f2bf(v.w));
  }
  for (int i = t; i < 2048; i += 512){
    int e = i >> 4, ng = i & 15;
    *(uint4*)(Ms + e*128 + ((ng ^ (e & 7)) << 3)) = *(const uint4*)(Mtb + e*128 + ng*8);
  }
  __syncthreads();
  const int wr = (w >> 1)*32, wc = (w & 1)*64;
  f32x4 acc[2][4] = {};
  for (int kc = 0; kc < 4; ++kc){
    bf16x8 a[2], bb[4];
    #pragma unroll
    for (int r = 0; r < 2; ++r) a[r] = ldfrag_sw(xs, wr + r*16, kc, lane);
    #pragma unroll
    for (int c = 0; c < 4; ++c) bb[c] = ldfrag_sw(Ms, wc + c*16, kc, lane);
    #pragma unroll
    for (int r = 0; r < 2; ++r)
      #pragma unroll
      for (int c = 0; c < 4; ++c)
        acc[r][c] = MFMA_BF16(a[r], bb[c], acc[r][c], 0, 0, 0);
  }
  __syncthreads();
  float* Sf = (float*)sm;   // [n][128] fp32, 64 KB
  #pragma unroll
  for (int r = 0; r < 2; ++r)
    #pragma unroll
    for (int c = 0; c < 4; ++c)
      #pragma unroll
      for (int reg = 0; reg < 4; ++reg)
        Sf[(wr + r*16 + quad*4 + reg)*128 + wc + c*16 + (lane & 15)] = acc[r][c][reg];
  __syncthreads();
  float* ob = out + ((size_t)b*NN + (size_t)nt*128)*DD;
  for (int i = t; i < 4096; i += 512){
    int n = i >> 5, c4 = (i & 31) * 4;
    *(float4*)(ob + (size_t)n*DD + c4) = *(const float4*)(Sf + n*128 + c4);
  }
}

extern "C" void kernel_launch(void* const* d_in, const int* in_sizes, int n_in,
                              void* d_out, int out_size, void* d_ws, size_t ws_size,
                              hipStream_t stream){
  const float* x  = (const float*)d_in[0];
  const float* Wk = (const float*)d_in[1];
  const float* Wq = (const float*)d_in[2];
  const float* Wv = (const float*)d_in[3];
  float* out = (float*)d_out;
  unsigned short* wsu = (unsigned short*)d_ws;
  unsigned short* Gp_bf = wsu;               // 4194304
  unsigned short* Mp_bf = wsu + 4194304;     // 4194304
  unsigned short* Pbf   = wsu + 8388608;     // 131072
  unsigned short* Mtbf  = wsu + 8519680;     // 524288

  kgkp<<<288, 512, 0, stream>>>(x, Wq, Wk, Gp_bf, Pbf);
  km2 <<<256, 512, 0, stream>>>(Gp_bf, Wv, Pbf, Mp_bf);
  kmr <<<256, 256, 0, stream>>>(Mp_bf, Mtbf);
  ko2 <<<512, 512, 0, stream>>>(x, Mtbf, out);
}